// Round 9
// baseline (234.269 us; speedup 1.0000x reference)
//
#include <hip/hip_runtime.h>
#include <hip/hip_fp16.h>
#include <math.h>

#ifndef M_PI
#define M_PI 3.14159265358979323846
#endif

#define NBLK  2048   // edge chunks (count/scatter blocks)
#define CHUNK 4096   // max edges per chunk (LDS payload buffer)
#define BSZ   512    // particles per bucket
#define BSH   9      // log2(BSZ)
#define NBK   512    // max buckets supported by LDS arrays

#define SCAN_GB   16                 // buckets per scan block
#define SCAN_TH   512                // threads in scan block
#define SCAN_ROWS (NBLK / SCAN_TH)   // rows per thread (4)

// ---------------------------------------------------------------- detect ----
__global__ void detect_idx_width(const unsigned* __restrict__ words,
                                 int* __restrict__ flag) {
    if (blockIdx.x == 0 && threadIdx.x == 0) {
        int is64 = 1;
#pragma unroll 1
        for (int k = 1; k < 2048; k += 2) {
            if (words[k] != 0u) { is64 = 0; break; }
        }
        *flag = is64;
    }
}

// ------------------------------------------------------------- pre table ----
// packed 8B: {h2(fac, rho), h2(vx, vy)} — 2MB table stays L2-resident.
__global__ __launch_bounds__(256) void precompute_particle(
    const float* __restrict__ fc_p, const float* __restrict__ area,
    const float* __restrict__ density, const float* __restrict__ restDensity,
    const float* __restrict__ velocity, uint2* __restrict__ pre, int N)
{
    int p = blockIdx.x * 256 + threadIdx.x;
    if (p >= N) return;
    const float fc = fc_p[0];
    const float rD = restDensity[p];
    const float2 v = ((const float2*)velocity)[p];
    __half2 fr = __floats2half2_rn(fc * rD * area[p], density[p] * rD);
    __half2 vv = __floats2half2_rn(v.x, v.y);
    pre[p] = make_uint2(*(unsigned*)&fr, *(unsigned*)&vv);
}

// ----------------------------------------------------------------- count ----
// table layout: [block][bucket] (row-major; coalesced row write per block).
__global__ __launch_bounds__(256) void pass_count(
    const void* __restrict__ nbr, const int* __restrict__ flag,
    unsigned* __restrict__ table, int E, int chunk, int NBnum)
{
    __shared__ unsigned cnt[NBK];
    for (int t = threadIdx.x; t < NBnum; t += 256) cnt[t] = 0u;
    __syncthreads();
    const int is64 = *flag;
    const long long s = (long long)blockIdx.x * chunk;
    long long e = s + chunk; if (e > E) e = E;
    if (is64) {
        const long long* ni = (const long long*)nbr;
        for (long long idx = s + threadIdx.x; idx < e; idx += 256)
            atomicAdd(&cnt[((int)ni[idx]) >> BSH], 1u);
    } else {
        const int* ni = (const int*)nbr;
        for (long long idx = s + threadIdx.x; idx < e; idx += 256)
            atomicAdd(&cnt[ni[idx] >> BSH], 1u);
    }
    __syncthreads();
    for (int t = threadIdx.x; t < NBnum; t += 256)
        table[(size_t)blockIdx.x * NBnum + t] = cnt[t];
}

// ------------------------------------------------- scan over blocks ---------
__global__ __launch_bounds__(SCAN_TH) void scan_blocks(
    const unsigned* __restrict__ table, unsigned* __restrict__ toff,
    unsigned* __restrict__ btot, int NBnum)
{
    __shared__ unsigned sums[SCAN_TH][SCAN_GB + 1];  // pad 17: conflict-free
    const int t = threadIdx.x;
    const int k0 = blockIdx.x * SCAN_GB;
    unsigned v[SCAN_ROWS][SCAN_GB];
    unsigned loc[SCAN_GB];
#pragma unroll
    for (int g = 0; g < SCAN_GB; ++g) loc[g] = 0u;
#pragma unroll
    for (int r = 0; r < SCAN_ROWS; ++r) {
        const size_t row = (size_t)(t * SCAN_ROWS + r) * NBnum;
#pragma unroll
        for (int g = 0; g < SCAN_GB; ++g) {
            unsigned x = (k0 + g < NBnum) ? table[row + k0 + g] : 0u;
            v[r][g] = x;
            loc[g] += x;
        }
    }
#pragma unroll
    for (int g = 0; g < SCAN_GB; ++g) sums[t][g] = loc[g];
    __syncthreads();
    for (int o = 1; o < SCAN_TH; o <<= 1) {
        unsigned m[SCAN_GB];
#pragma unroll
        for (int g = 0; g < SCAN_GB; ++g) m[g] = (t >= o) ? sums[t - o][g] : 0u;
        __syncthreads();
#pragma unroll
        for (int g = 0; g < SCAN_GB; ++g) sums[t][g] += m[g];
        __syncthreads();
    }
    unsigned pre[SCAN_GB];
#pragma unroll
    for (int g = 0; g < SCAN_GB; ++g) pre[g] = t ? sums[t - 1][g] : 0u;
#pragma unroll
    for (int r = 0; r < SCAN_ROWS; ++r) {
        const size_t row = (size_t)(t * SCAN_ROWS + r) * NBnum;
#pragma unroll
        for (int g = 0; g < SCAN_GB; ++g) {
            if (k0 + g < NBnum) toff[row + k0 + g] = pre[g];
            pre[g] += v[r][g];
        }
    }
    if (t == SCAN_TH - 1) {
#pragma unroll
        for (int g = 0; g < SCAN_GB; ++g)
            if (k0 + g < NBnum) btot[k0 + g] = sums[t][g];
    }
}

// -------------------------------------------------- scan bucket totals ------
__global__ void scan_buckets(const unsigned* __restrict__ btot,
                             unsigned* __restrict__ bstart, int NBnum)
{
    __shared__ unsigned buf[1024];
    const int t = threadIdx.x;
    buf[t] = btot[t];
    __syncthreads();
    for (int o = 1; o < NBnum; o <<= 1) {
        unsigned v = (t >= o) ? buf[t - o] : 0u;
        __syncthreads();
        buf[t] += v;
        __syncthreads();
    }
    bstart[t] = (t == 0) ? 0u : buf[t - 1];
    if (t == NBnum - 1) bstart[NBnum] = buf[t];
}

// --------------------------------------------------------------- scatter ----
// (round-4 form, known-good) payload.x = j | i_local<<22, payload.y = bits(q)
__global__ __launch_bounds__(256) void pass_scatter(
    const void* __restrict__ nbr, const float* __restrict__ rad,
    const int* __restrict__ flag, const unsigned* __restrict__ table,
    const unsigned* __restrict__ toff, const unsigned* __restrict__ bstart,
    int2* __restrict__ jq, int E, int chunk, int NBnum)
{
    __shared__ int2 buf[CHUNK];      // 32 KB payload staging
    __shared__ unsigned cur[NBK];    // counts -> scan -> cursors -> incl ends
    __shared__ unsigned dst[NBK];    // global dest base per bucket

    const int b = blockIdx.x;
    const long long s = (long long)b * chunk;
    long long e = s + chunk; if (e > E) e = E;
    const int n = (int)(e - s);
    if (n <= 0) return;              // uniform across block
    const int tid = threadIdx.x;

    for (int k = tid; k < NBnum; k += 256) {
        cur[k] = table[(size_t)b * NBnum + k];
        dst[k] = bstart[k] + toff[(size_t)b * NBnum + k];
    }
    __syncthreads();

    // inclusive Hillis-Steele scan of cur[0..NBnum), 2 elems/thread
    for (int o = 1; o < NBnum; o <<= 1) {
        const int t0 = tid, t1 = tid + 256;
        unsigned v0 = (t0 < NBnum) ? cur[t0] : 0u;
        unsigned m0 = (t0 >= o && t0 < NBnum) ? cur[t0 - o] : 0u;
        unsigned v1 = (t1 < NBnum) ? cur[t1] : 0u;
        unsigned m1 = (t1 >= o && t1 < NBnum) ? cur[t1 - o] : 0u;
        __syncthreads();
        if (t0 < NBnum) cur[t0] = v0 + m0;
        if (t1 < NBnum) cur[t1] = v1 + m1;
        __syncthreads();
    }
    // shift inclusive -> exclusive
    {
        const int t0 = tid, t1 = tid + 256;
        unsigned x0 = (t0 < NBnum) ? (t0 ? cur[t0 - 1] : 0u) : 0u;
        unsigned x1 = (t1 < NBnum) ? cur[t1 - 1] : 0u;
        __syncthreads();
        if (t0 < NBnum) cur[t0] = x0;
        if (t1 < NBnum) cur[t1] = x1;
        __syncthreads();
    }

    // phase B: stream edges, place payloads at locally-sorted LDS positions
    const int is64 = *flag;
    if (is64) {
        const long long* ni = (const long long*)nbr;
        const long long* nj = ni + E;
        for (long long idx = s + tid; idx < e; idx += 256) {
            int i = (int)ni[idx];
            int j = (int)nj[idx];
            float q = rad[idx];
            unsigned pos = atomicAdd(&cur[i >> BSH], 1u);
            buf[pos] = make_int2(j | ((i & (BSZ - 1)) << 22),
                                 __float_as_int(q));
        }
    } else {
        const int* ni = (const int*)nbr;
        const int* nj = ni + E;
        for (long long idx = s + tid; idx < e; idx += 256) {
            int i = ni[idx];
            int j = nj[idx];
            float q = rad[idx];
            unsigned pos = atomicAdd(&cur[i >> BSH], 1u);
            buf[pos] = make_int2(j | ((i & (BSZ - 1)) << 22),
                                 __float_as_int(q));
        }
    }
    __syncthreads();
    // now cur[k] == inclusive end of bucket k's local run

    // phase C: linear write-out; binary search smallest k with cur[k] > t
    for (int t = tid; t < n; t += 256) {
        int lo = 0, hi = NBnum - 1;
        while (lo < hi) {
            int mid = (lo + hi) >> 1;
            if (cur[mid] > (unsigned)t) hi = mid; else lo = mid + 1;
        }
        unsigned start = lo ? cur[lo - 1] : 0u;
        jq[dst[lo] + ((unsigned)t - start)] = buf[t];
    }
}

// ---------------------------------------------------------------- reduce ----
// Non-temporal jq stream (keeps packed pre L2-resident), 8B packed gathers,
// split accx/accy LDS accumulators (all 32 banks), ×4 strip-mine.
__global__ __launch_bounds__(512) void pass_reduce(
    const int2* __restrict__ jq, const uint2* __restrict__ pre,
    const unsigned* __restrict__ bstart, float2* __restrict__ out, int N)
{
    __shared__ float4 plds[BSZ];
    __shared__ float accx[BSZ];
    __shared__ float accy[BSZ];
    const int k = blockIdx.x;
    const int base = k << BSH;
    const int tid = threadIdx.x;
    {
        int p = base + tid;
        if (p < N) {
            uint2 pv = pre[p];
            float2 fr = __half22float2(*(__half2*)&pv.x);
            float2 vv = __half22float2(*(__half2*)&pv.y);
            plds[tid] = make_float4(fr.x, fr.y, vv.x, vv.y);
        } else {
            plds[tid] = make_float4(0.f, 0.f, 0.f, 0.f);
        }
        accx[tid] = 0.f;
        accy[tid] = 0.f;
    }
    __syncthreads();
    const unsigned s = bstart[k];
    const unsigned e = bstart[k + 1];
    const unsigned cnt = e - s;
    const unsigned nfull = cnt >> 11;          // tiles of 2048 = 512thr x 4

    for (unsigned r = 0; r < nfull; ++r) {
        const unsigned idx = s + (r << 11) + ((unsigned)tid << 2);
        // 4 independent non-temporal payload loads (evict-first in L2)
        const long long w0 = __builtin_nontemporal_load((const long long*)(jq + idx));
        const long long w1 = __builtin_nontemporal_load((const long long*)(jq + idx + 1));
        const long long w2 = __builtin_nontemporal_load((const long long*)(jq + idx + 2));
        const long long w3 = __builtin_nontemporal_load((const long long*)(jq + idx + 3));
        const int x0 = (int)w0, x1 = (int)w1, x2 = (int)w2, x3 = (int)w3;
        const int j0 = x0 & ((1 << 22) - 1), il0 = (x0 >> 22) & (BSZ - 1);
        const int j1 = x1 & ((1 << 22) - 1), il1 = (x1 >> 22) & (BSZ - 1);
        const int j2 = x2 & ((1 << 22) - 1), il2 = (x2 >> 22) & (BSZ - 1);
        const int j3 = x3 & ((1 << 22) - 1), il3 = (x3 >> 22) & (BSZ - 1);
        // 4 independent 8B gathers (L2-resident table)
        const uint2 g0 = pre[j0];
        const uint2 g1 = pre[j1];
        const uint2 g2 = pre[j2];
        const uint2 g3 = pre[j3];
#define REDUCE_BODY(gj, qbits, il)                                           \
        {                                                                    \
            const float q = __int_as_float((int)(qbits >> 32));              \
            const float2 fr = __half22float2(*(const __half2*)&gj.x);        \
            const float2 vv = __half22float2(*(const __half2*)&gj.y);        \
            const float4 pi = plds[il];                                      \
            const float b = fmaxf(1.0f - q, 0.0f);                           \
            const float b2 = b * b;                                          \
            const float w = (b2 * b2) * fmaf(4.0f, q, 1.0f);                 \
            const float sc = fr.x * w / (pi.y + fr.y);                       \
            atomicAdd(&accx[il], sc * (vv.x - pi.z));                        \
            atomicAdd(&accy[il], sc * (vv.y - pi.w));                        \
        }
        REDUCE_BODY(g0, w0, il0)
        REDUCE_BODY(g1, w1, il1)
        REDUCE_BODY(g2, w2, il2)
        REDUCE_BODY(g3, w3, il3)
    }
    // scalar tail
    for (unsigned idx = s + (nfull << 11) + tid; idx < e; idx += 512) {
        const int2 pk = jq[idx];
        const int j = pk.x & ((1 << 22) - 1);
        const int il = (pk.x >> 22) & (BSZ - 1);
        const uint2 gj = pre[j];
        const long long qb = ((long long)pk.y) << 32;
        REDUCE_BODY(gj, qb, il)
    }
#undef REDUCE_BODY
    __syncthreads();
    {
        int p = base + tid;
        if (p < N) {
            // fold the 2*C Wendland constant here: C = 7/(pi*h^2); support
            // baked on host side is not available, so scale via bstart? No:
            // scale applied below using constant passed implicitly — see
            // host: we pre-multiplied fac by fc only; apply 2*C at the end.
            out[p] = make_float2(accx[tid], accy[tid]);
        }
    }
}

// ------------------------------------------------------------ final scale ---
// out *= 2*C  (C = 7/(pi h^2)) — cheaper than per-edge multiply.
__global__ __launch_bounds__(256) void pass_scale(
    float2* __restrict__ out, const float* __restrict__ support_p, int N)
{
    int p = blockIdx.x * 256 + threadIdx.x;
    if (p >= N) return;
    const float h = support_p[0];
    const float C = 7.0f / ((float)M_PI * h * h);
    float2 v = out[p];
    out[p] = make_float2(v.x * 2.0f * C, v.y * 2.0f * C);
}

// ------------------------------------------------- fallback (atomic path) ---
__global__ __launch_bounds__(256) void xsph_edge_kernel(
    const float* __restrict__ fc_p, const float* __restrict__ area,
    const float* __restrict__ density, const float* __restrict__ restDensity,
    const float* __restrict__ velocity, const float* __restrict__ rad,
    const void* __restrict__ nbr, const float* __restrict__ support_p,
    const int* __restrict__ flag, float* __restrict__ out, int E)
{
    const int is64 = *flag;
    const float fc = fc_p[0];
    const float h = support_p[0];
    const float C = 7.0f / ((float)M_PI * h * h);
    const long long e0 =
        (long long)(blockIdx.x * (long long)blockDim.x + threadIdx.x) * 4;
    if (e0 >= (long long)E) return;
    int ii[4], jj[4];
    if (is64) {
        const long long* ni = (const long long*)nbr;
        const long long* nj = ni + E;
#pragma unroll
        for (int k = 0; k < 4; ++k) { ii[k] = (int)ni[e0 + k]; jj[k] = (int)nj[e0 + k]; }
    } else {
        const int* ni = (const int*)nbr;
        const int* nj = ni + E;
        int4 iv = *(const int4*)(ni + e0);
        int4 jv = *(const int4*)(nj + e0);
        ii[0] = iv.x; ii[1] = iv.y; ii[2] = iv.z; ii[3] = iv.w;
        jj[0] = jv.x; jj[1] = jv.y; jj[2] = jv.z; jj[3] = jv.w;
    }
    float4 qv = *(const float4*)(rad + e0);
    float qq[4] = {qv.x, qv.y, qv.z, qv.w};
#pragma unroll
    for (int k = 0; k < 4; ++k) {
        const int i = ii[k], j = jj[k];
        const float rDi = restDensity[i], rDj = restDensity[j];
        const float fac = fc * rDj * area[j];
        const float rho_i = density[i] * rDi, rho_j = density[j] * rDj;
        const float2 vi = *(const float2*)(velocity + 2 * i);
        const float2 vj = *(const float2*)(velocity + 2 * j);
        const float q = qq[k];
        const float b = fmaxf(1.0f - q, 0.0f);
        const float b2 = b * b;
        const float w = C * (b2 * b2) * fmaf(4.0f, q, 1.0f);
        const float s = fac * 2.0f * w / (rho_i + rho_j);
        unsafeAtomicAdd(&out[2 * i],     s * (vj.x - vi.x));
        unsafeAtomicAdd(&out[2 * i + 1], s * (vj.y - vi.y));
    }
}

// ------------------------------------------------------------------ host ----
extern "C" void kernel_launch(void* const* d_in, const int* in_sizes, int n_in,
                              void* d_out, int out_size, void* d_ws, size_t ws_size,
                              hipStream_t stream) {
    const float* fc          = (const float*)d_in[0];
    const float* area        = (const float*)d_in[1];
    const float* density     = (const float*)d_in[2];
    const float* restDensity = (const float*)d_in[3];
    const float* velocity    = (const float*)d_in[4];
    const float* rad         = (const float*)d_in[5];
    const void*  nbr         = d_in[6];
    const float* support     = (const float*)d_in[7];

    const int N = in_sizes[1];
    const int E = in_sizes[5];
    const int NBnum = (N + BSZ - 1) / BSZ;
    const int chunk = (int)(((long long)E + NBLK - 1) / NBLK);

    // ---- workspace layout (16B-aligned sections) ----
    char* ws = (char*)d_ws;
    size_t off = 0;
    int* flag = (int*)(ws + off);               off += 16;
    uint2* pre = (uint2*)(ws + off);            off += (size_t)N * 8;
    off = (off + 15) & ~(size_t)15;
    unsigned* table = (unsigned*)(ws + off);    off += (size_t)NBLK * NBnum * 4;
    off = (off + 15) & ~(size_t)15;
    unsigned* toff = (unsigned*)(ws + off);     off += (size_t)NBLK * NBnum * 4;
    off = (off + 15) & ~(size_t)15;
    unsigned* btot = (unsigned*)(ws + off);     off += (size_t)NBnum * 4;
    off = (off + 15) & ~(size_t)15;
    unsigned* bstart = (unsigned*)(ws + off);   off += (size_t)(NBnum + 1) * 4;
    off = (off + 15) & ~(size_t)15;
    int2* jq = (int2*)(ws + off);               off += (size_t)E * 8;
    const size_t need = off;

    detect_idx_width<<<1, 1, 0, stream>>>((const unsigned*)nbr, flag);

    const bool can_sort =
        (ws_size >= need) && (NBnum <= NBK) && (N <= (1 << 22)) &&
        (chunk <= CHUNK) && (E > 0);

    if (can_sort) {
        precompute_particle<<<(N + 255) / 256, 256, 0, stream>>>(
            fc, area, density, restDensity, velocity, pre, N);
        pass_count<<<NBLK, 256, 0, stream>>>(nbr, flag, table, E, chunk, NBnum);
        scan_blocks<<<(NBnum + SCAN_GB - 1) / SCAN_GB, SCAN_TH, 0, stream>>>(
            table, toff, btot, NBnum);
        scan_buckets<<<1, NBnum, 0, stream>>>(btot, bstart, NBnum);
        pass_scatter<<<NBLK, 256, 0, stream>>>(nbr, rad, flag, table, toff,
                                               bstart, jq, E, chunk, NBnum);
        pass_reduce<<<NBnum, 512, 0, stream>>>(jq, pre, bstart,
                                               (float2*)d_out, N);
        pass_scale<<<(N + 255) / 256, 256, 0, stream>>>(
            (float2*)d_out, support, N);
    } else {
        hipMemsetAsync(d_out, 0, (size_t)out_size * sizeof(float), stream);
        const int threads = 256;
        const long long nthreads = ((long long)E + 3) / 4;
        const int blocks = (int)((nthreads + threads - 1) / threads);
        xsph_edge_kernel<<<blocks, threads, 0, stream>>>(
            fc, area, density, restDensity, velocity, rad, nbr, support, flag,
            (float*)d_out, E);
    }
}

// Round 10
// 233.233 us; speedup vs baseline: 1.0044x; 1.0044x over previous
//
#include <hip/hip_runtime.h>
#include <hip/hip_fp16.h>
#include <math.h>

#ifndef M_PI
#define M_PI 3.14159265358979323846
#endif

#define NBLK  2048   // edge chunks (count/scatter blocks)
#define CHUNK 4096   // max edges per chunk (LDS payload buffer)
#define BSZ   512    // particles per bucket
#define BSH   9      // log2(BSZ)
#define NBK   512    // max buckets supported by LDS arrays

#define SCAN_GB   16                 // buckets per scan block
#define SCAN_TH   512                // threads in scan block
#define SCAN_ROWS (NBLK / SCAN_TH)   // rows per thread (4)

// ---------------------------------------------------------------- detect ----
__global__ void detect_idx_width(const unsigned* __restrict__ words,
                                 int* __restrict__ flag) {
    if (blockIdx.x == 0 && threadIdx.x == 0) {
        int is64 = 1;
#pragma unroll 1
        for (int k = 1; k < 2048; k += 2) {
            if (words[k] != 0u) { is64 = 0; break; }
        }
        *flag = is64;
    }
}

// ------------------------------------------------------------- pre table ----
// packed 8B: {h2(fac, rho), h2(vx, vy)} — 2MB table stays L2-resident.
__global__ __launch_bounds__(256) void precompute_particle(
    const float* __restrict__ fc_p, const float* __restrict__ area,
    const float* __restrict__ density, const float* __restrict__ restDensity,
    const float* __restrict__ velocity, uint2* __restrict__ pre, int N)
{
    int p = blockIdx.x * 256 + threadIdx.x;
    if (p >= N) return;
    const float fc = fc_p[0];
    const float rD = restDensity[p];
    const float2 v = ((const float2*)velocity)[p];
    __half2 fr = __floats2half2_rn(fc * rD * area[p], density[p] * rD);
    __half2 vv = __floats2half2_rn(v.x, v.y);
    pre[p] = make_uint2(*(unsigned*)&fr, *(unsigned*)&vv);
}

// ----------------------------------------------------------------- count ----
// table layout: [block][bucket] (row-major; coalesced row write per block).
__global__ __launch_bounds__(256) void pass_count(
    const void* __restrict__ nbr, const int* __restrict__ flag,
    unsigned* __restrict__ table, int E, int chunk, int NBnum)
{
    __shared__ unsigned cnt[NBK];
    for (int t = threadIdx.x; t < NBnum; t += 256) cnt[t] = 0u;
    __syncthreads();
    const int is64 = *flag;
    const long long s = (long long)blockIdx.x * chunk;
    long long e = s + chunk; if (e > E) e = E;
    if (is64) {
        const long long* ni = (const long long*)nbr;
        for (long long idx = s + threadIdx.x; idx < e; idx += 256)
            atomicAdd(&cnt[((int)ni[idx]) >> BSH], 1u);
    } else {
        const int* ni = (const int*)nbr;
        for (long long idx = s + threadIdx.x; idx < e; idx += 256)
            atomicAdd(&cnt[ni[idx] >> BSH], 1u);
    }
    __syncthreads();
    for (int t = threadIdx.x; t < NBnum; t += 256)
        table[(size_t)blockIdx.x * NBnum + t] = cnt[t];
}

// ------------------------------------------------- scan over blocks ---------
__global__ __launch_bounds__(SCAN_TH) void scan_blocks(
    const unsigned* __restrict__ table, unsigned* __restrict__ toff,
    unsigned* __restrict__ btot, int NBnum)
{
    __shared__ unsigned sums[SCAN_TH][SCAN_GB + 1];  // pad 17: conflict-free
    const int t = threadIdx.x;
    const int k0 = blockIdx.x * SCAN_GB;
    unsigned v[SCAN_ROWS][SCAN_GB];
    unsigned loc[SCAN_GB];
#pragma unroll
    for (int g = 0; g < SCAN_GB; ++g) loc[g] = 0u;
#pragma unroll
    for (int r = 0; r < SCAN_ROWS; ++r) {
        const size_t row = (size_t)(t * SCAN_ROWS + r) * NBnum;
#pragma unroll
        for (int g = 0; g < SCAN_GB; ++g) {
            unsigned x = (k0 + g < NBnum) ? table[row + k0 + g] : 0u;
            v[r][g] = x;
            loc[g] += x;
        }
    }
#pragma unroll
    for (int g = 0; g < SCAN_GB; ++g) sums[t][g] = loc[g];
    __syncthreads();
    for (int o = 1; o < SCAN_TH; o <<= 1) {
        unsigned m[SCAN_GB];
#pragma unroll
        for (int g = 0; g < SCAN_GB; ++g) m[g] = (t >= o) ? sums[t - o][g] : 0u;
        __syncthreads();
#pragma unroll
        for (int g = 0; g < SCAN_GB; ++g) sums[t][g] += m[g];
        __syncthreads();
    }
    unsigned pre[SCAN_GB];
#pragma unroll
    for (int g = 0; g < SCAN_GB; ++g) pre[g] = t ? sums[t - 1][g] : 0u;
#pragma unroll
    for (int r = 0; r < SCAN_ROWS; ++r) {
        const size_t row = (size_t)(t * SCAN_ROWS + r) * NBnum;
#pragma unroll
        for (int g = 0; g < SCAN_GB; ++g) {
            if (k0 + g < NBnum) toff[row + k0 + g] = pre[g];
            pre[g] += v[r][g];
        }
    }
    if (t == SCAN_TH - 1) {
#pragma unroll
        for (int g = 0; g < SCAN_GB; ++g)
            if (k0 + g < NBnum) btot[k0 + g] = sums[t][g];
    }
}

// -------------------------------------------------- scan bucket totals ------
__global__ void scan_buckets(const unsigned* __restrict__ btot,
                             unsigned* __restrict__ bstart, int NBnum)
{
    __shared__ unsigned buf[1024];
    const int t = threadIdx.x;
    buf[t] = btot[t];
    __syncthreads();
    for (int o = 1; o < NBnum; o <<= 1) {
        unsigned v = (t >= o) ? buf[t - o] : 0u;
        __syncthreads();
        buf[t] += v;
        __syncthreads();
    }
    bstart[t] = (t == 0) ? 0u : buf[t - 1];
    if (t == NBnum - 1) bstart[NBnum] = buf[t];
}

// --------------------------------------------------------------- scatter ----
// v3: phase B records each payload's bucket (bkt[pos]); phase C uses direct
// lookup (3 independent LDS reads) instead of a 9-step serialized binary
// search. payload.x = j | i_local<<22, payload.y = bits(q).
// LDS = 32K buf + 8K bkt + 2K cur + 2K loff + 2K dst = 46KB -> 3 blocks/CU.
__global__ __launch_bounds__(256) void pass_scatter(
    const void* __restrict__ nbr, const float* __restrict__ rad,
    const int* __restrict__ flag, const unsigned* __restrict__ table,
    const unsigned* __restrict__ toff, const unsigned* __restrict__ bstart,
    int2* __restrict__ jq, int E, int chunk, int NBnum)
{
    __shared__ int2 buf[CHUNK];        // payload staging
    __shared__ unsigned short bkt[CHUNK]; // bucket id of each staged payload
    __shared__ unsigned cur[NBK];      // counts -> scan -> cursors
    __shared__ unsigned loff[NBK];     // exclusive local starts (snapshot)
    __shared__ unsigned dst[NBK];      // global dest base per bucket

    const int b = blockIdx.x;
    const long long s = (long long)b * chunk;
    long long e = s + chunk; if (e > E) e = E;
    const int n = (int)(e - s);
    if (n <= 0) return;              // uniform across block
    const int tid = threadIdx.x;

    for (int k = tid; k < NBnum; k += 256) {
        cur[k] = table[(size_t)b * NBnum + k];
        dst[k] = bstart[k] + toff[(size_t)b * NBnum + k];
    }
    __syncthreads();

    // inclusive Hillis-Steele scan of cur[0..NBnum), 2 elems/thread
    for (int o = 1; o < NBnum; o <<= 1) {
        const int t0 = tid, t1 = tid + 256;
        unsigned v0 = (t0 < NBnum) ? cur[t0] : 0u;
        unsigned m0 = (t0 >= o && t0 < NBnum) ? cur[t0 - o] : 0u;
        unsigned v1 = (t1 < NBnum) ? cur[t1] : 0u;
        unsigned m1 = (t1 >= o && t1 < NBnum) ? cur[t1 - o] : 0u;
        __syncthreads();
        if (t0 < NBnum) cur[t0] = v0 + m0;
        if (t1 < NBnum) cur[t1] = v1 + m1;
        __syncthreads();
    }
    // shift inclusive -> exclusive, snapshot starts into loff
    {
        const int t0 = tid, t1 = tid + 256;
        unsigned x0 = (t0 < NBnum) ? (t0 ? cur[t0 - 1] : 0u) : 0u;
        unsigned x1 = (t1 < NBnum) ? cur[t1 - 1] : 0u;
        __syncthreads();
        if (t0 < NBnum) { cur[t0] = x0; loff[t0] = x0; }
        if (t1 < NBnum) { cur[t1] = x1; loff[t1] = x1; }
        __syncthreads();
    }

    // phase B: stream edges, place payloads + bucket ids at sorted positions
    const int is64 = *flag;
    if (is64) {
        const long long* ni = (const long long*)nbr;
        const long long* nj = ni + E;
        for (long long idx = s + tid; idx < e; idx += 256) {
            int i = (int)ni[idx];
            int j = (int)nj[idx];
            float q = rad[idx];
            int bk = i >> BSH;
            unsigned pos = atomicAdd(&cur[bk], 1u);
            buf[pos] = make_int2(j | ((i & (BSZ - 1)) << 22),
                                 __float_as_int(q));
            bkt[pos] = (unsigned short)bk;
        }
    } else {
        const int* ni = (const int*)nbr;
        const int* nj = ni + E;
        for (long long idx = s + tid; idx < e; idx += 256) {
            int i = ni[idx];
            int j = nj[idx];
            float q = rad[idx];
            int bk = i >> BSH;
            unsigned pos = atomicAdd(&cur[bk], 1u);
            buf[pos] = make_int2(j | ((i & (BSZ - 1)) << 22),
                                 __float_as_int(q));
            bkt[pos] = (unsigned short)bk;
        }
    }
    __syncthreads();

    // phase C: linear write-out with direct bucket lookup (no binary search)
    for (int t = tid; t < n; t += 256) {
        const int bk = bkt[t];
        jq[dst[bk] + ((unsigned)t - loff[bk])] = buf[t];
    }
}

// ---------------------------------------------------------------- reduce ----
// (round-9 form, unchanged) Non-temporal jq stream, 8B packed gathers,
// split accx/accy LDS accumulators, ×4 strip-mine.
__global__ __launch_bounds__(512) void pass_reduce(
    const int2* __restrict__ jq, const uint2* __restrict__ pre,
    const unsigned* __restrict__ bstart, float2* __restrict__ out, int N)
{
    __shared__ float4 plds[BSZ];
    __shared__ float accx[BSZ];
    __shared__ float accy[BSZ];
    const int k = blockIdx.x;
    const int base = k << BSH;
    const int tid = threadIdx.x;
    {
        int p = base + tid;
        if (p < N) {
            uint2 pv = pre[p];
            float2 fr = __half22float2(*(__half2*)&pv.x);
            float2 vv = __half22float2(*(__half2*)&pv.y);
            plds[tid] = make_float4(fr.x, fr.y, vv.x, vv.y);
        } else {
            plds[tid] = make_float4(0.f, 0.f, 0.f, 0.f);
        }
        accx[tid] = 0.f;
        accy[tid] = 0.f;
    }
    __syncthreads();
    const unsigned s = bstart[k];
    const unsigned e = bstart[k + 1];
    const unsigned cnt = e - s;
    const unsigned nfull = cnt >> 11;          // tiles of 2048 = 512thr x 4

    for (unsigned r = 0; r < nfull; ++r) {
        const unsigned idx = s + (r << 11) + ((unsigned)tid << 2);
        const long long w0 = __builtin_nontemporal_load((const long long*)(jq + idx));
        const long long w1 = __builtin_nontemporal_load((const long long*)(jq + idx + 1));
        const long long w2 = __builtin_nontemporal_load((const long long*)(jq + idx + 2));
        const long long w3 = __builtin_nontemporal_load((const long long*)(jq + idx + 3));
        const int x0 = (int)w0, x1 = (int)w1, x2 = (int)w2, x3 = (int)w3;
        const int j0 = x0 & ((1 << 22) - 1), il0 = (x0 >> 22) & (BSZ - 1);
        const int j1 = x1 & ((1 << 22) - 1), il1 = (x1 >> 22) & (BSZ - 1);
        const int j2 = x2 & ((1 << 22) - 1), il2 = (x2 >> 22) & (BSZ - 1);
        const int j3 = x3 & ((1 << 22) - 1), il3 = (x3 >> 22) & (BSZ - 1);
        const uint2 g0 = pre[j0];
        const uint2 g1 = pre[j1];
        const uint2 g2 = pre[j2];
        const uint2 g3 = pre[j3];
#define REDUCE_BODY(gj, qbits, il)                                           \
        {                                                                    \
            const float q = __int_as_float((int)(qbits >> 32));              \
            const float2 fr = __half22float2(*(const __half2*)&gj.x);        \
            const float2 vv = __half22float2(*(const __half2*)&gj.y);        \
            const float4 pi = plds[il];                                      \
            const float b = fmaxf(1.0f - q, 0.0f);                           \
            const float b2 = b * b;                                          \
            const float w = (b2 * b2) * fmaf(4.0f, q, 1.0f);                 \
            const float sc = fr.x * w / (pi.y + fr.y);                       \
            atomicAdd(&accx[il], sc * (vv.x - pi.z));                        \
            atomicAdd(&accy[il], sc * (vv.y - pi.w));                        \
        }
        REDUCE_BODY(g0, w0, il0)
        REDUCE_BODY(g1, w1, il1)
        REDUCE_BODY(g2, w2, il2)
        REDUCE_BODY(g3, w3, il3)
    }
    // scalar tail
    for (unsigned idx = s + (nfull << 11) + tid; idx < e; idx += 512) {
        const int2 pk = jq[idx];
        const int j = pk.x & ((1 << 22) - 1);
        const int il = (pk.x >> 22) & (BSZ - 1);
        const uint2 gj = pre[j];
        const long long qb = ((long long)pk.y) << 32;
        REDUCE_BODY(gj, qb, il)
    }
#undef REDUCE_BODY
    __syncthreads();
    {
        int p = base + tid;
        if (p < N) out[p] = make_float2(accx[tid], accy[tid]);
    }
}

// ------------------------------------------------------------ final scale ---
// out *= 2*C  (C = 7/(pi h^2)) — cheaper than per-edge multiply.
__global__ __launch_bounds__(256) void pass_scale(
    float2* __restrict__ out, const float* __restrict__ support_p, int N)
{
    int p = blockIdx.x * 256 + threadIdx.x;
    if (p >= N) return;
    const float h = support_p[0];
    const float C = 7.0f / ((float)M_PI * h * h);
    float2 v = out[p];
    out[p] = make_float2(v.x * 2.0f * C, v.y * 2.0f * C);
}

// ------------------------------------------------- fallback (atomic path) ---
__global__ __launch_bounds__(256) void xsph_edge_kernel(
    const float* __restrict__ fc_p, const float* __restrict__ area,
    const float* __restrict__ density, const float* __restrict__ restDensity,
    const float* __restrict__ velocity, const float* __restrict__ rad,
    const void* __restrict__ nbr, const float* __restrict__ support_p,
    const int* __restrict__ flag, float* __restrict__ out, int E)
{
    const int is64 = *flag;
    const float fc = fc_p[0];
    const float h = support_p[0];
    const float C = 7.0f / ((float)M_PI * h * h);
    const long long e0 =
        (long long)(blockIdx.x * (long long)blockDim.x + threadIdx.x) * 4;
    if (e0 >= (long long)E) return;
    int ii[4], jj[4];
    if (is64) {
        const long long* ni = (const long long*)nbr;
        const long long* nj = ni + E;
#pragma unroll
        for (int k = 0; k < 4; ++k) { ii[k] = (int)ni[e0 + k]; jj[k] = (int)nj[e0 + k]; }
    } else {
        const int* ni = (const int*)nbr;
        const int* nj = ni + E;
        int4 iv = *(const int4*)(ni + e0);
        int4 jv = *(const int4*)(nj + e0);
        ii[0] = iv.x; ii[1] = iv.y; ii[2] = iv.z; ii[3] = iv.w;
        jj[0] = jv.x; jj[1] = jv.y; jj[2] = jv.z; jj[3] = jv.w;
    }
    float4 qv = *(const float4*)(rad + e0);
    float qq[4] = {qv.x, qv.y, qv.z, qv.w};
#pragma unroll
    for (int k = 0; k < 4; ++k) {
        const int i = ii[k], j = jj[k];
        const float rDi = restDensity[i], rDj = restDensity[j];
        const float fac = fc * rDj * area[j];
        const float rho_i = density[i] * rDi, rho_j = density[j] * rDj;
        const float2 vi = *(const float2*)(velocity + 2 * i);
        const float2 vj = *(const float2*)(velocity + 2 * j);
        const float q = qq[k];
        const float b = fmaxf(1.0f - q, 0.0f);
        const float b2 = b * b;
        const float w = C * (b2 * b2) * fmaf(4.0f, q, 1.0f);
        const float s = fac * 2.0f * w / (rho_i + rho_j);
        unsafeAtomicAdd(&out[2 * i],     s * (vj.x - vi.x));
        unsafeAtomicAdd(&out[2 * i + 1], s * (vj.y - vi.y));
    }
}

// ------------------------------------------------------------------ host ----
extern "C" void kernel_launch(void* const* d_in, const int* in_sizes, int n_in,
                              void* d_out, int out_size, void* d_ws, size_t ws_size,
                              hipStream_t stream) {
    const float* fc          = (const float*)d_in[0];
    const float* area        = (const float*)d_in[1];
    const float* density     = (const float*)d_in[2];
    const float* restDensity = (const float*)d_in[3];
    const float* velocity    = (const float*)d_in[4];
    const float* rad         = (const float*)d_in[5];
    const void*  nbr         = d_in[6];
    const float* support     = (const float*)d_in[7];

    const int N = in_sizes[1];
    const int E = in_sizes[5];
    const int NBnum = (N + BSZ - 1) / BSZ;
    const int chunk = (int)(((long long)E + NBLK - 1) / NBLK);

    // ---- workspace layout (16B-aligned sections) ----
    char* ws = (char*)d_ws;
    size_t off = 0;
    int* flag = (int*)(ws + off);               off += 16;
    uint2* pre = (uint2*)(ws + off);            off += (size_t)N * 8;
    off = (off + 15) & ~(size_t)15;
    unsigned* table = (unsigned*)(ws + off);    off += (size_t)NBLK * NBnum * 4;
    off = (off + 15) & ~(size_t)15;
    unsigned* toff = (unsigned*)(ws + off);     off += (size_t)NBLK * NBnum * 4;
    off = (off + 15) & ~(size_t)15;
    unsigned* btot = (unsigned*)(ws + off);     off += (size_t)NBnum * 4;
    off = (off + 15) & ~(size_t)15;
    unsigned* bstart = (unsigned*)(ws + off);   off += (size_t)(NBnum + 1) * 4;
    off = (off + 15) & ~(size_t)15;
    int2* jq = (int2*)(ws + off);               off += (size_t)E * 8;
    const size_t need = off;

    detect_idx_width<<<1, 1, 0, stream>>>((const unsigned*)nbr, flag);

    const bool can_sort =
        (ws_size >= need) && (NBnum <= NBK) && (N <= (1 << 22)) &&
        (chunk <= CHUNK) && (E > 0);

    if (can_sort) {
        precompute_particle<<<(N + 255) / 256, 256, 0, stream>>>(
            fc, area, density, restDensity, velocity, pre, N);
        pass_count<<<NBLK, 256, 0, stream>>>(nbr, flag, table, E, chunk, NBnum);
        scan_blocks<<<(NBnum + SCAN_GB - 1) / SCAN_GB, SCAN_TH, 0, stream>>>(
            table, toff, btot, NBnum);
        scan_buckets<<<1, NBnum, 0, stream>>>(btot, bstart, NBnum);
        pass_scatter<<<NBLK, 256, 0, stream>>>(nbr, rad, flag, table, toff,
                                               bstart, jq, E, chunk, NBnum);
        pass_reduce<<<NBnum, 512, 0, stream>>>(jq, pre, bstart,
                                               (float2*)d_out, N);
        pass_scale<<<(N + 255) / 256, 256, 0, stream>>>(
            (float2*)d_out, support, N);
    } else {
        hipMemsetAsync(d_out, 0, (size_t)out_size * sizeof(float), stream);
        const int threads = 256;
        const long long nthreads = ((long long)E + 3) / 4;
        const int blocks = (int)((nthreads + threads - 1) / threads);
        xsph_edge_kernel<<<blocks, threads, 0, stream>>>(
            fc, area, density, restDensity, velocity, rad, nbr, support, flag,
            (float*)d_out, E);
    }
}

// Round 11
// 231.447 us; speedup vs baseline: 1.0122x; 1.0077x over previous
//
#include <hip/hip_runtime.h>
#include <hip/hip_fp16.h>
#include <math.h>

#ifndef M_PI
#define M_PI 3.14159265358979323846
#endif

#define NBLK  2048   // edge chunks (count/scatter blocks)
#define CHUNK 4096   // max edges per chunk (LDS payload buffer)
#define BSZ   512    // particles per bucket
#define BSH   9      // log2(BSZ)
#define NBK   512    // max buckets supported by LDS arrays

#define SCAN_GB   16                 // buckets per scan block
#define SCAN_TH   512                // threads in scan block
#define SCAN_ROWS (NBLK / SCAN_TH)   // rows per thread (4)

// ---------------------------------------------------------------- detect ----
// Parallel probe: 256 threads scan 1024 odd (high) words; any nonzero -> int32.
__global__ __launch_bounds__(256) void detect_idx_width(
    const unsigned* __restrict__ words, int* __restrict__ flag) {
    __shared__ int nz;
    if (threadIdx.x == 0) nz = 0;
    __syncthreads();
    unsigned acc = 0u;
#pragma unroll
    for (int r = 0; r < 4; ++r) {
        int k = 1 + 2 * (threadIdx.x + r * 256);
        acc |= words[k];
    }
    if (acc) atomicOr(&nz, 1);
    __syncthreads();
    if (threadIdx.x == 0) *flag = nz ? 0 : 1;
}

// ------------------------------------------------------------- pre table ----
// packed 8B: {h2(fac, rho), h2(vx, vy)} — 2MB table stays L2-resident.
__global__ __launch_bounds__(256) void precompute_particle(
    const float* __restrict__ fc_p, const float* __restrict__ area,
    const float* __restrict__ density, const float* __restrict__ restDensity,
    const float* __restrict__ velocity, uint2* __restrict__ pre, int N)
{
    int p = blockIdx.x * 256 + threadIdx.x;
    if (p >= N) return;
    const float fc = fc_p[0];
    const float rD = restDensity[p];
    const float2 v = ((const float2*)velocity)[p];
    __half2 fr = __floats2half2_rn(fc * rD * area[p], density[p] * rD);
    __half2 vv = __floats2half2_rn(v.x, v.y);
    pre[p] = make_uint2(*(unsigned*)&fr, *(unsigned*)&vv);
}

// ----------------------------------------------------------------- count ----
// For is64, read only the LOW dword of each index (value < 2^31 per detect):
// halves the stream. table layout: [block][bucket].
__global__ __launch_bounds__(256) void pass_count(
    const void* __restrict__ nbr, const int* __restrict__ flag,
    unsigned* __restrict__ table, int E, int chunk, int NBnum)
{
    __shared__ unsigned cnt[NBK];
    for (int t = threadIdx.x; t < NBnum; t += 256) cnt[t] = 0u;
    __syncthreads();
    const int is64 = *flag;
    const long long s = (long long)blockIdx.x * chunk;
    long long e = s + chunk; if (e > E) e = E;
    if (is64) {
        const int* ni = (const int*)nbr;   // low dwords at even offsets
        for (long long idx = s + threadIdx.x; idx < e; idx += 256)
            atomicAdd(&cnt[ni[2 * idx] >> BSH], 1u);
    } else {
        const int* ni = (const int*)nbr;
        for (long long idx = s + threadIdx.x; idx < e; idx += 256)
            atomicAdd(&cnt[ni[idx] >> BSH], 1u);
    }
    __syncthreads();
    for (int t = threadIdx.x; t < NBnum; t += 256)
        table[(size_t)blockIdx.x * NBnum + t] = cnt[t];
}

// ------------------------------------------------- scan over blocks ---------
__global__ __launch_bounds__(SCAN_TH) void scan_blocks(
    const unsigned* __restrict__ table, unsigned* __restrict__ toff,
    unsigned* __restrict__ btot, int NBnum)
{
    __shared__ unsigned sums[SCAN_TH][SCAN_GB + 1];  // pad 17: conflict-free
    const int t = threadIdx.x;
    const int k0 = blockIdx.x * SCAN_GB;
    unsigned v[SCAN_ROWS][SCAN_GB];
    unsigned loc[SCAN_GB];
#pragma unroll
    for (int g = 0; g < SCAN_GB; ++g) loc[g] = 0u;
#pragma unroll
    for (int r = 0; r < SCAN_ROWS; ++r) {
        const size_t row = (size_t)(t * SCAN_ROWS + r) * NBnum;
#pragma unroll
        for (int g = 0; g < SCAN_GB; ++g) {
            unsigned x = (k0 + g < NBnum) ? table[row + k0 + g] : 0u;
            v[r][g] = x;
            loc[g] += x;
        }
    }
#pragma unroll
    for (int g = 0; g < SCAN_GB; ++g) sums[t][g] = loc[g];
    __syncthreads();
    for (int o = 1; o < SCAN_TH; o <<= 1) {
        unsigned m[SCAN_GB];
#pragma unroll
        for (int g = 0; g < SCAN_GB; ++g) m[g] = (t >= o) ? sums[t - o][g] : 0u;
        __syncthreads();
#pragma unroll
        for (int g = 0; g < SCAN_GB; ++g) sums[t][g] += m[g];
        __syncthreads();
    }
    unsigned pre[SCAN_GB];
#pragma unroll
    for (int g = 0; g < SCAN_GB; ++g) pre[g] = t ? sums[t - 1][g] : 0u;
#pragma unroll
    for (int r = 0; r < SCAN_ROWS; ++r) {
        const size_t row = (size_t)(t * SCAN_ROWS + r) * NBnum;
#pragma unroll
        for (int g = 0; g < SCAN_GB; ++g) {
            if (k0 + g < NBnum) toff[row + k0 + g] = pre[g];
            pre[g] += v[r][g];
        }
    }
    if (t == SCAN_TH - 1) {
#pragma unroll
        for (int g = 0; g < SCAN_GB; ++g)
            if (k0 + g < NBnum) btot[k0 + g] = sums[t][g];
    }
}

// -------------------------------------------------- scan bucket totals ------
__global__ void scan_buckets(const unsigned* __restrict__ btot,
                             unsigned* __restrict__ bstart, int NBnum)
{
    __shared__ unsigned buf[1024];
    const int t = threadIdx.x;
    buf[t] = btot[t];
    __syncthreads();
    for (int o = 1; o < NBnum; o <<= 1) {
        unsigned v = (t >= o) ? buf[t - o] : 0u;
        __syncthreads();
        buf[t] += v;
        __syncthreads();
    }
    bstart[t] = (t == 0) ? 0u : buf[t - 1];
    if (t == NBnum - 1) bstart[NBnum] = buf[t];
}

// --------------------------------------------------------------- scatter ----
// Low-dword reads for is64 (halves ni/nj streams). Direct bucket lookup in
// phase C (round-10 form). payload.x = j | i_local<<22, payload.y = bits(q).
__global__ __launch_bounds__(256) void pass_scatter(
    const void* __restrict__ nbr, const float* __restrict__ rad,
    const int* __restrict__ flag, const unsigned* __restrict__ table,
    const unsigned* __restrict__ toff, const unsigned* __restrict__ bstart,
    int2* __restrict__ jq, int E, int chunk, int NBnum)
{
    __shared__ int2 buf[CHUNK];           // payload staging
    __shared__ unsigned short bkt[CHUNK]; // bucket id of each staged payload
    __shared__ unsigned cur[NBK];         // counts -> scan -> cursors
    __shared__ unsigned loff[NBK];        // exclusive local starts (snapshot)
    __shared__ unsigned dst[NBK];         // global dest base per bucket

    const int b = blockIdx.x;
    const long long s = (long long)b * chunk;
    long long e = s + chunk; if (e > E) e = E;
    const int n = (int)(e - s);
    if (n <= 0) return;              // uniform across block
    const int tid = threadIdx.x;

    for (int k = tid; k < NBnum; k += 256) {
        cur[k] = table[(size_t)b * NBnum + k];
        dst[k] = bstart[k] + toff[(size_t)b * NBnum + k];
    }
    __syncthreads();

    // inclusive Hillis-Steele scan of cur[0..NBnum), 2 elems/thread
    for (int o = 1; o < NBnum; o <<= 1) {
        const int t0 = tid, t1 = tid + 256;
        unsigned v0 = (t0 < NBnum) ? cur[t0] : 0u;
        unsigned m0 = (t0 >= o && t0 < NBnum) ? cur[t0 - o] : 0u;
        unsigned v1 = (t1 < NBnum) ? cur[t1] : 0u;
        unsigned m1 = (t1 >= o && t1 < NBnum) ? cur[t1 - o] : 0u;
        __syncthreads();
        if (t0 < NBnum) cur[t0] = v0 + m0;
        if (t1 < NBnum) cur[t1] = v1 + m1;
        __syncthreads();
    }
    // shift inclusive -> exclusive, snapshot starts into loff
    {
        const int t0 = tid, t1 = tid + 256;
        unsigned x0 = (t0 < NBnum) ? (t0 ? cur[t0 - 1] : 0u) : 0u;
        unsigned x1 = (t1 < NBnum) ? cur[t1 - 1] : 0u;
        __syncthreads();
        if (t0 < NBnum) { cur[t0] = x0; loff[t0] = x0; }
        if (t1 < NBnum) { cur[t1] = x1; loff[t1] = x1; }
        __syncthreads();
    }

    // phase B: stream edges, place payloads + bucket ids at sorted positions
    const int is64 = *flag;
    if (is64) {
        const int* ni = (const int*)nbr;          // low dwords, stride 2
        const int* nj = ni + 2 * (size_t)E;
        for (long long idx = s + tid; idx < e; idx += 256) {
            int i = ni[2 * idx];
            int j = nj[2 * idx];
            float q = rad[idx];
            int bk = i >> BSH;
            unsigned pos = atomicAdd(&cur[bk], 1u);
            buf[pos] = make_int2(j | ((i & (BSZ - 1)) << 22),
                                 __float_as_int(q));
            bkt[pos] = (unsigned short)bk;
        }
    } else {
        const int* ni = (const int*)nbr;
        const int* nj = ni + E;
        for (long long idx = s + tid; idx < e; idx += 256) {
            int i = ni[idx];
            int j = nj[idx];
            float q = rad[idx];
            int bk = i >> BSH;
            unsigned pos = atomicAdd(&cur[bk], 1u);
            buf[pos] = make_int2(j | ((i & (BSZ - 1)) << 22),
                                 __float_as_int(q));
            bkt[pos] = (unsigned short)bk;
        }
    }
    __syncthreads();

    // phase C: linear write-out with direct bucket lookup
    for (int t = tid; t < n; t += 256) {
        const int bk = bkt[t];
        jq[dst[bk] + ((unsigned)t - loff[bk])] = buf[t];
    }
}

// ---------------------------------------------------------------- reduce ----
// Non-temporal jq stream, 8B packed gathers, split accx/accy accumulators,
// ×4 strip-mine. Final 2*C Wendland scale folded into the output write.
__global__ __launch_bounds__(512) void pass_reduce(
    const int2* __restrict__ jq, const uint2* __restrict__ pre,
    const unsigned* __restrict__ bstart, const float* __restrict__ support_p,
    float2* __restrict__ out, int N)
{
    __shared__ float4 plds[BSZ];
    __shared__ float accx[BSZ];
    __shared__ float accy[BSZ];
    const int k = blockIdx.x;
    const int base = k << BSH;
    const int tid = threadIdx.x;
    {
        int p = base + tid;
        if (p < N) {
            uint2 pv = pre[p];
            float2 fr = __half22float2(*(__half2*)&pv.x);
            float2 vv = __half22float2(*(__half2*)&pv.y);
            plds[tid] = make_float4(fr.x, fr.y, vv.x, vv.y);
        } else {
            plds[tid] = make_float4(0.f, 0.f, 0.f, 0.f);
        }
        accx[tid] = 0.f;
        accy[tid] = 0.f;
    }
    __syncthreads();
    const unsigned s = bstart[k];
    const unsigned e = bstart[k + 1];
    const unsigned cnt = e - s;
    const unsigned nfull = cnt >> 11;          // tiles of 2048 = 512thr x 4

    for (unsigned r = 0; r < nfull; ++r) {
        const unsigned idx = s + (r << 11) + ((unsigned)tid << 2);
        const long long w0 = __builtin_nontemporal_load((const long long*)(jq + idx));
        const long long w1 = __builtin_nontemporal_load((const long long*)(jq + idx + 1));
        const long long w2 = __builtin_nontemporal_load((const long long*)(jq + idx + 2));
        const long long w3 = __builtin_nontemporal_load((const long long*)(jq + idx + 3));
        const int x0 = (int)w0, x1 = (int)w1, x2 = (int)w2, x3 = (int)w3;
        const int j0 = x0 & ((1 << 22) - 1), il0 = (x0 >> 22) & (BSZ - 1);
        const int j1 = x1 & ((1 << 22) - 1), il1 = (x1 >> 22) & (BSZ - 1);
        const int j2 = x2 & ((1 << 22) - 1), il2 = (x2 >> 22) & (BSZ - 1);
        const int j3 = x3 & ((1 << 22) - 1), il3 = (x3 >> 22) & (BSZ - 1);
        const uint2 g0 = pre[j0];
        const uint2 g1 = pre[j1];
        const uint2 g2 = pre[j2];
        const uint2 g3 = pre[j3];
#define REDUCE_BODY(gj, qbits, il)                                           \
        {                                                                    \
            const float q = __int_as_float((int)(qbits >> 32));              \
            const float2 fr = __half22float2(*(const __half2*)&gj.x);        \
            const float2 vv = __half22float2(*(const __half2*)&gj.y);        \
            const float4 pi = plds[il];                                      \
            const float b = fmaxf(1.0f - q, 0.0f);                           \
            const float b2 = b * b;                                          \
            const float w = (b2 * b2) * fmaf(4.0f, q, 1.0f);                 \
            const float sc = fr.x * w / (pi.y + fr.y);                       \
            atomicAdd(&accx[il], sc * (vv.x - pi.z));                        \
            atomicAdd(&accy[il], sc * (vv.y - pi.w));                        \
        }
        REDUCE_BODY(g0, w0, il0)
        REDUCE_BODY(g1, w1, il1)
        REDUCE_BODY(g2, w2, il2)
        REDUCE_BODY(g3, w3, il3)
    }
    // scalar tail
    for (unsigned idx = s + (nfull << 11) + tid; idx < e; idx += 512) {
        const int2 pk = jq[idx];
        const int j = pk.x & ((1 << 22) - 1);
        const int il = (pk.x >> 22) & (BSZ - 1);
        const uint2 gj = pre[j];
        const long long qb = ((long long)pk.y) << 32;
        REDUCE_BODY(gj, qb, il)
    }
#undef REDUCE_BODY
    __syncthreads();
    {
        int p = base + tid;
        if (p < N) {
            const float h = support_p[0];
            const float twoC = 2.0f * 7.0f / ((float)M_PI * h * h);
            out[p] = make_float2(accx[tid] * twoC, accy[tid] * twoC);
        }
    }
}

// ------------------------------------------------- fallback (atomic path) ---
__global__ __launch_bounds__(256) void xsph_edge_kernel(
    const float* __restrict__ fc_p, const float* __restrict__ area,
    const float* __restrict__ density, const float* __restrict__ restDensity,
    const float* __restrict__ velocity, const float* __restrict__ rad,
    const void* __restrict__ nbr, const float* __restrict__ support_p,
    const int* __restrict__ flag, float* __restrict__ out, int E)
{
    const int is64 = *flag;
    const float fc = fc_p[0];
    const float h = support_p[0];
    const float C = 7.0f / ((float)M_PI * h * h);
    const long long e0 =
        (long long)(blockIdx.x * (long long)blockDim.x + threadIdx.x) * 4;
    if (e0 >= (long long)E) return;
    int ii[4], jj[4];
    if (is64) {
        const long long* ni = (const long long*)nbr;
        const long long* nj = ni + E;
#pragma unroll
        for (int k = 0; k < 4; ++k) { ii[k] = (int)ni[e0 + k]; jj[k] = (int)nj[e0 + k]; }
    } else {
        const int* ni = (const int*)nbr;
        const int* nj = ni + E;
        int4 iv = *(const int4*)(ni + e0);
        int4 jv = *(const int4*)(nj + e0);
        ii[0] = iv.x; ii[1] = iv.y; ii[2] = iv.z; ii[3] = iv.w;
        jj[0] = jv.x; jj[1] = jv.y; jj[2] = jv.z; jj[3] = jv.w;
    }
    float4 qv = *(const float4*)(rad + e0);
    float qq[4] = {qv.x, qv.y, qv.z, qv.w};
#pragma unroll
    for (int k = 0; k < 4; ++k) {
        const int i = ii[k], j = jj[k];
        const float rDi = restDensity[i], rDj = restDensity[j];
        const float fac = fc * rDj * area[j];
        const float rho_i = density[i] * rDi, rho_j = density[j] * rDj;
        const float2 vi = *(const float2*)(velocity + 2 * i);
        const float2 vj = *(const float2*)(velocity + 2 * j);
        const float q = qq[k];
        const float b = fmaxf(1.0f - q, 0.0f);
        const float b2 = b * b;
        const float w = C * (b2 * b2) * fmaf(4.0f, q, 1.0f);
        const float s = fac * 2.0f * w / (rho_i + rho_j);
        unsafeAtomicAdd(&out[2 * i],     s * (vj.x - vi.x));
        unsafeAtomicAdd(&out[2 * i + 1], s * (vj.y - vi.y));
    }
}

// ------------------------------------------------------------------ host ----
extern "C" void kernel_launch(void* const* d_in, const int* in_sizes, int n_in,
                              void* d_out, int out_size, void* d_ws, size_t ws_size,
                              hipStream_t stream) {
    const float* fc          = (const float*)d_in[0];
    const float* area        = (const float*)d_in[1];
    const float* density     = (const float*)d_in[2];
    const float* restDensity = (const float*)d_in[3];
    const float* velocity    = (const float*)d_in[4];
    const float* rad         = (const float*)d_in[5];
    const void*  nbr         = d_in[6];
    const float* support     = (const float*)d_in[7];

    const int N = in_sizes[1];
    const int E = in_sizes[5];
    const int NBnum = (N + BSZ - 1) / BSZ;
    const int chunk = (int)(((long long)E + NBLK - 1) / NBLK);

    // ---- workspace layout (16B-aligned sections) ----
    char* ws = (char*)d_ws;
    size_t off = 0;
    int* flag = (int*)(ws + off);               off += 16;
    uint2* pre = (uint2*)(ws + off);            off += (size_t)N * 8;
    off = (off + 15) & ~(size_t)15;
    unsigned* table = (unsigned*)(ws + off);    off += (size_t)NBLK * NBnum * 4;
    off = (off + 15) & ~(size_t)15;
    unsigned* toff = (unsigned*)(ws + off);     off += (size_t)NBLK * NBnum * 4;
    off = (off + 15) & ~(size_t)15;
    unsigned* btot = (unsigned*)(ws + off);     off += (size_t)NBnum * 4;
    off = (off + 15) & ~(size_t)15;
    unsigned* bstart = (unsigned*)(ws + off);   off += (size_t)(NBnum + 1) * 4;
    off = (off + 15) & ~(size_t)15;
    int2* jq = (int2*)(ws + off);               off += (size_t)E * 8;
    const size_t need = off;

    detect_idx_width<<<1, 256, 0, stream>>>((const unsigned*)nbr, flag);

    const bool can_sort =
        (ws_size >= need) && (NBnum <= NBK) && (N <= (1 << 22)) &&
        (chunk <= CHUNK) && (E > 2048) ;

    if (can_sort) {
        precompute_particle<<<(N + 255) / 256, 256, 0, stream>>>(
            fc, area, density, restDensity, velocity, pre, N);
        pass_count<<<NBLK, 256, 0, stream>>>(nbr, flag, table, E, chunk, NBnum);
        scan_blocks<<<(NBnum + SCAN_GB - 1) / SCAN_GB, SCAN_TH, 0, stream>>>(
            table, toff, btot, NBnum);
        scan_buckets<<<1, NBnum, 0, stream>>>(btot, bstart, NBnum);
        pass_scatter<<<NBLK, 256, 0, stream>>>(nbr, rad, flag, table, toff,
                                               bstart, jq, E, chunk, NBnum);
        pass_reduce<<<NBnum, 512, 0, stream>>>(jq, pre, bstart, support,
                                               (float2*)d_out, N);
    } else {
        hipMemsetAsync(d_out, 0, (size_t)out_size * sizeof(float), stream);
        const int threads = 256;
        const long long nthreads = ((long long)E + 3) / 4;
        const int blocks = (int)((nthreads + threads - 1) / threads);
        xsph_edge_kernel<<<blocks, threads, 0, stream>>>(
            fc, area, density, restDensity, velocity, rad, nbr, support, flag,
            (float*)d_out, E);
    }
}